// Round 13
// baseline (79.829 us; speedup 1.0000x reference)
//
#include <hip/hip_runtime.h>

// Pipeline_8400956031319: dual greedy NMS (8192 det + 8192 rpn, IOU>0.6,
// index order) + argmax masking.
//
// R12 rev — two dispatches; scanpair's row scan rebuilt as wave-coalesced
// LDS staging (R12 issued 4 scalar dword loads per 36B/24B-strided row:
// ~36 lines touched per wave-instr for 256B used => ~600MB L2 traffic).
// Now each wave loads a 64-row group as 3 coalesced dwordx4 wave-instrs
// (every line fetched once), parks in per-wave LDS scratch, lanes read
// their row's coords from LDS (stride 9 conflict-free, stride 6 = 2-way =
// free). Wave-synchronous: no block barriers in the scan loop.
//
//   K1 scanpair (512 blocks = (cell,set), 512 thr): coalesced scan ->
//     stage 3x3 neighborhood of 128px cells in LDS (box <=120 < 128 =>
//     only 3x3 neighborhoods can overlap) -> flattened pair loop, exact
//     ref IOU, emit edges (i<<13|j, once via orig_a < orig_b) to private
//     per-block regions.
//   K2 solve_epi (32 blocks x 1024): gather edges to LDS, Jacobi fixpoint
//     keep[j] = !(exists i<j edge with keep[i]) (unique fixpoint == greedy
//     NMS; iterate until stable), then write 512-row output slice.

constexpr int NROWS = 8192;
constexpr int NKW   = 256;      // keep words (u32) per set
constexpr unsigned BCAP = 1536; // staged neighborhood cap (mean ~288)
constexpr unsigned ACAP = 512;  // cell-member cap (mean ~32)
constexpr unsigned RCAP = 2048; // per-block edge region cap (mean ~12)
constexpr unsigned ELDS = 16384;// solve LDS edge cache
#define IOU_T 0.6f

// ws layout: cnts[2][256] u32 @ 0 ; edges[2*256][RCAP] u32 @ 4096
constexpr size_t OFF_EDGES = 4096;

// ---------------------------------------------------------------------------
// K1: fused coalesced scan + pair. grid = (256 cells, 2 sets) x 512 threads.
// ---------------------------------------------------------------------------
__global__ __launch_bounds__(512) void scanpair_kernel(
    const float* __restrict__ det, const float* __restrict__ rpn,
    unsigned* __restrict__ cnts, unsigned* __restrict__ edges)
{
  const int cellid = blockIdx.x, set = blockIdx.y;
  const float* src  = (set == 0) ? det : rpn;
  const int    strd = (set == 0) ? 9 : 6;
  unsigned* myedges = edges + ((size_t)(set * 256 + cellid)) * RCAP;
  const int cx = cellid & 15, cy = cellid >> 4;

  __shared__ float Bx1[BCAP], By1[BCAP], Bx2[BCAP], By2[BCAP], Bar[BCAP];
  __shared__ unsigned Bid[BCAP];
  __shared__ unsigned aList[ACAP];
  __shared__ float wsbuf[8][576];   // per-wave staging (64 rows x <=9 floats)
  __shared__ unsigned bCnt, aCnt, eCnt, ovf;

  const int t = threadIdx.x;
  const int wv = t >> 6, lane = t & 63;
  if (t == 0) { bCnt = 0u; aCnt = 0u; eCnt = 0u; ovf = 0u; }
  __syncthreads();

  // --- coalesced scan: 128 groups of 64 rows; wave wv owns groups wv+8k ---
  const int nch = strd * 16;                 // float4 chunks per group (144/96)
  const float4* src4 = (const float4*)src;   // hipMalloc'd => 16B aligned
  float4* wb = (float4*)wsbuf[wv];

  // prologue: load group wv
  float4 c0, c1, c2;
  {
    const size_t gb = (size_t)wv * nch;
    c0 = src4[gb + lane];
    c1 = (lane + 64  < nch) ? src4[gb + lane + 64]  : make_float4(0, 0, 0, 0);
    c2 = (lane + 128 < nch) ? src4[gb + lane + 128] : make_float4(0, 0, 0, 0);
  }

  for (int step = 0; step < 16; ++step) {
    const int g = wv + step * 8;
    // stage current group to this wave's LDS scratch
    wb[lane] = c0;
    if (lane + 64  < nch) wb[lane + 64]  = c1;
    if (lane + 128 < nch) wb[lane + 128] = c2;
    // issue next group's coalesced loads (in flight during classify/append)
    float4 n0, n1, n2;
    if (step < 15) {
      const size_t gb = (size_t)(g + 8) * nch;
      n0 = src4[gb + lane];
      n1 = (lane + 64  < nch) ? src4[gb + lane + 64]  : make_float4(0, 0, 0, 0);
      n2 = (lane + 128 < nch) ? src4[gb + lane + 128] : make_float4(0, 0, 0, 0);
    }
    // wave-local LDS visibility (same wave wrote it; no block barrier needed)
    asm volatile("s_waitcnt lgkmcnt(0)" ::: "memory");
    {
      const float* row = &wsbuf[wv][strd * lane + 1];
      const float x1 = row[0], y1 = row[1], x2 = row[2], y2 = row[3];
      const int r = g * 64 + lane;
      const float cxe = 0.5f * (x1 + x2), cye = 0.5f * (y1 + y2);
      const int ccx = min(15, max(0, (int)(cxe * (1.0f / 128.0f))));
      const int ccy = min(15, max(0, (int)(cye * (1.0f / 128.0f))));
      const int dx = ccx - cx, dy = ccy - cy;
      if (dx >= -1 && dx <= 1 && dy >= -1 && dy <= 1) {
        const unsigned s = atomicAdd(&bCnt, 1u);
        if (s < BCAP) {
          Bx1[s] = x1; By1[s] = y1; Bx2[s] = x2; By2[s] = y2;
          Bar[s] = fmaxf(x2 - x1, 0.0f) * fmaxf(y2 - y1, 0.0f); // ref area
          Bid[s] = (unsigned)r;
          if (dx == 0 && dy == 0) {
            const unsigned as = atomicAdd(&aCnt, 1u);
            if (as < ACAP) aList[as] = s; else atomicOr(&ovf, 1u);
          }
        } else atomicOr(&ovf, 1u);
      }
    }
    c0 = n0; c1 = n1; c2 = n2;
  }
  __syncthreads();

  const unsigned nb = min(bCnt, BCAP);
  const unsigned na = min(aCnt, ACAP);

  if (!ovf) {
    // flattened pair phase: all tests independent, LDS-resident
    const unsigned tot = na * nb;
    for (unsigned p = t; p < tot; p += 512) {
      const unsigned ai = p / nb, x = p - ai * nb;
      const unsigned s = aList[ai];
      const unsigned ia = Bid[s], ib = Bid[x];
      if (ia < ib) {                                   // emit-once; skips self
        const float ix1 = fmaxf(Bx1[s], Bx1[x]), iy1 = fmaxf(By1[s], By1[x]);
        const float ix2 = fminf(Bx2[s], Bx2[x]), iy2 = fminf(By2[s], By2[x]);
        const float inter = fmaxf(ix2 - ix1, 0.0f) * fmaxf(iy2 - iy1, 0.0f);
        if (inter > 0.0f) {
          const float uni = Bar[s] + Bar[x] - inter;          // ref order
          const float iou = inter / fmaxf(uni, 1e-9f);        // ref expr
          if (iou > IOU_T) {
            const unsigned slot = atomicAdd(&eCnt, 1u);       // LDS atomic
            if (slot < RCAP) myedges[slot] = (ia << 13) | ib;
          }
        }
      }
    }
  } else {
    // exact fallback (never taken for this data): a = rows in this cell,
    // b = ALL rows; out-of-neighborhood pairs have inter==0 geometrically,
    // so semantics are identical to the fast path.
    for (int ra = 0; ra < NROWS; ++ra) {
      const float* pa = src + (size_t)ra * strd + 1;
      const float ax1 = pa[0], ay1 = pa[1], ax2 = pa[2], ay2 = pa[3];
      const float cxe = 0.5f * (ax1 + ax2), cye = 0.5f * (ay1 + ay2);
      const int ccx = min(15, max(0, (int)(cxe * (1.0f / 128.0f))));
      const int ccy = min(15, max(0, (int)(cye * (1.0f / 128.0f))));
      if (ccx != cx || ccy != cy) continue;            // uniform skip
      const float aar = fmaxf(ax2 - ax1, 0.0f) * fmaxf(ay2 - ay1, 0.0f);
      for (int rb = t; rb < NROWS; rb += 512) {
        if ((unsigned)ra >= (unsigned)rb) continue;
        const float* pb = src + (size_t)rb * strd + 1;
        const float bx1 = pb[0], by1 = pb[1], bx2 = pb[2], by2 = pb[3];
        const float ix1 = fmaxf(ax1, bx1), iy1 = fmaxf(ay1, by1);
        const float ix2 = fminf(ax2, bx2), iy2 = fminf(ay2, by2);
        const float inter = fmaxf(ix2 - ix1, 0.0f) * fmaxf(iy2 - iy1, 0.0f);
        if (inter > 0.0f) {
          const float bar = fmaxf(bx2 - bx1, 0.0f) * fmaxf(by2 - by1, 0.0f);
          const float uni = aar + bar - inter;
          const float iou = inter / fmaxf(uni, 1e-9f);
          if (iou > IOU_T) {
            const unsigned slot = atomicAdd(&eCnt, 1u);
            if (slot < RCAP) myedges[slot] = ((unsigned)ra << 13) | (unsigned)rb;
          }
        }
      }
    }
  }
  __syncthreads();
  if (t == 0) cnts[set * 256 + cellid] = min(eCnt, RCAP);
}

// ---------------------------------------------------------------------------
// K2: fixpoint + epilogue. grid = 32 blocks x 1024. set = blk>>4; each block
// solves its set's fixpoint (redundantly, ~3k edges) then writes rows
// [slice*512, slice*512+512) of its outputs.
// ---------------------------------------------------------------------------
__global__ __launch_bounds__(1024) void solve_epi_kernel(
    const float* __restrict__ det, const float* __restrict__ rpn,
    const unsigned* __restrict__ cnts, const unsigned* __restrict__ edges,
    float* __restrict__ out)
{
  const int blk = blockIdx.x;
  const int set = blk >> 4;
  const int slice = blk & 15;
  const unsigned* gedges = edges + (size_t)set * 256 * RCAP;

  __shared__ unsigned eL[ELDS];
  __shared__ unsigned rcnt[256], roff[256];
  __shared__ unsigned kbuf[2][NKW];
  __shared__ int changed[2];
  __shared__ unsigned Etot_sh;

  const int t = threadIdx.x;
  if (t < 256) rcnt[t] = min(cnts[set * 256 + t], RCAP);
  __syncthreads();

  // wave0 shuffle-scan of 256 region counts (4/lane)
  if (t < 64) {
    const unsigned h0 = rcnt[4 * t], h1 = rcnt[4 * t + 1];
    const unsigned h2 = rcnt[4 * t + 2], h3 = rcnt[4 * t + 3];
    const unsigned lsum = h0 + h1 + h2 + h3;
    unsigned incl = lsum;
    #pragma unroll
    for (int d = 1; d < 64; d <<= 1) {
      const unsigned v = __shfl_up(incl, d);
      if (t >= d) incl += v;
    }
    const unsigned base = incl - lsum;
    roff[4 * t] = base;               roff[4 * t + 1] = base + h0;
    roff[4 * t + 2] = base + h0 + h1; roff[4 * t + 3] = base + h0 + h1 + h2;
    if (t == 63) Etot_sh = incl;
  }
  if (t < NKW) kbuf[0][t] = 0xFFFFFFFFu;
  __syncthreads();

  const unsigned Etot = Etot_sh;
  const bool cached = (Etot <= ELDS);
  if (cached) {                 // gather: 4 threads per region (~3 loads ea)
    const unsigned rg = (unsigned)t >> 2, ln = (unsigned)t & 3u;
    const unsigned c = rcnt[rg], o = roff[rg];
    for (unsigned k = ln; k < c; k += 4u)
      eL[o + k] = gedges[(size_t)rg * RCAP + k];
  }
  __syncthreads();

  int cur = 0;
  for (int round = 0; round < NROWS + 8; ++round) {
    const int nxt = cur ^ 1;
    if (t == 0) changed[round & 1] = 0;
    if (t < NKW) kbuf[nxt][t] = 0xFFFFFFFFu;
    __syncthreads();

    if (cached) {
      for (unsigned e = t; e < Etot; e += 1024) {
        const unsigned pk = eL[e];
        const unsigned i = pk >> 13, j = pk & 8191u;
        if ((kbuf[cur][i >> 5] >> (i & 31)) & 1u)
          atomicAnd(&kbuf[nxt][j >> 5], ~(1u << (j & 31)));
      }
    } else {                    // exact slow path (never taken)
      for (unsigned r = (unsigned)t >> 2; r < 256u; r += 256u) {
        const unsigned c = rcnt[r];
        for (unsigned k = (unsigned)t & 3u; k < c; k += 4u) {
          const unsigned pk = gedges[(size_t)r * RCAP + k];
          const unsigned i = pk >> 13, j = pk & 8191u;
          if ((kbuf[cur][i >> 5] >> (i & 31)) & 1u)
            atomicAnd(&kbuf[nxt][j >> 5], ~(1u << (j & 31)));
        }
      }
    }
    __syncthreads();

    if (t < NKW && kbuf[nxt][t] != kbuf[cur][t]) changed[round & 1] = 1;
    __syncthreads();

    cur = nxt;
    if (!changed[round & 1]) break;  // F(x)==x -> the unique fixpoint
  }

  // epilogue slice: 512 rows per block
  const int r0 = slice * 512;
  if (set == 0) {
    for (int i = r0 + t; i < r0 + 512; i += 1024) {
      const bool kd = (kbuf[cur][i >> 5] >> (i & 31)) & 1u;
      const float* p = det + (size_t)i * 9;
      const float sc0 = p[5], sc1 = p[6], sc2 = p[7], sc3 = p[8];
      int am = 0; float best = sc0;
      if (sc1 > best) { best = sc1; am = 1; }   // first-max, like jnp.argmax
      if (sc2 > best) { best = sc2; am = 2; }
      if (sc3 > best) { best = sc3; am = 3; }
      const float vm = (kd && am != 0) ? 1.0f : 0.0f;
      const float im = (kd && am == 0) ? 1.0f : 0.0f;
      float* o0 = out + (size_t)i * 9;
      float* o1 = out + (size_t)NROWS * 9 + (size_t)i * 9;
      #pragma unroll
      for (int c = 0; c < 9; ++c) { const float v = p[c]; o0[c] = v * vm; o1[c] = v * im; }
    }
  } else {
    for (int i = r0 + t; i < r0 + 512; i += 1024) {
      const bool kr = (kbuf[cur][i >> 5] >> (i & 31)) & 1u;
      const float rm = kr ? 1.0f : 0.0f;
      const float* q = rpn + (size_t)i * 6;
      float* o2 = out + (size_t)NROWS * 18 + (size_t)i * 6;
      #pragma unroll
      for (int c = 0; c < 6; ++c) o2[c] = q[c] * rm;
    }
  }
}

// ---------------------------------------------------------------------------
extern "C" void kernel_launch(void* const* d_in, const int* in_sizes, int n_in,
                              void* d_out, int out_size, void* d_ws, size_t ws_size,
                              hipStream_t stream)
{
  const float* det = (const float*)d_in[0];   // 8192 x 9 fp32
  const float* rpn = (const float*)d_in[1];   // 8192 x 6 fp32
  float* out = (float*)d_out;                 // 8192*9 + 8192*9 + 8192*6 fp32

  char* ws = (char*)d_ws;
  unsigned* cnts  = (unsigned*)ws;            // [2][256] u32
  unsigned* edges = (unsigned*)(ws + OFF_EDGES);

  dim3 g1(256, 2);
  scanpair_kernel<<<g1, 512, 0, stream>>>(det, rpn, cnts, edges);
  solve_epi_kernel<<<32, 1024, 0, stream>>>(det, rpn, cnts, edges, out);
}